// Round 1
// 6644.032 us; speedup vs baseline: 2.0175x; 2.0175x over previous
//
#include <hip/hip_runtime.h>
#include <hip/hip_bf16.h>

#define B_   64
#define T_   1024
#define D_   512
#define H_   512
#define G4H  2048
#define K_   1024

typedef __bf16 bf16x8 __attribute__((ext_vector_type(8)));
typedef float  f32x4  __attribute__((ext_vector_type(4)));

// workspace layout (bytes)
#define OFF_XT  0ull                                            // x transposed (T,B,D) bf16: 64 MiB
#define OFF_H1  (OFF_XT + (unsigned long long)T_*B_*D_*2)       // h1 history (T,B,H) bf16
#define OFF_H2  (OFF_H1 + (unsigned long long)T_*B_*H_*2)       // h2 history (T,B,H) bf16
#define OFF_WP  (OFF_H2 + (unsigned long long)T_*B_*H_*2)       // W' (L,4H,K) bf16 = [Wx|Wh]
#define OFF_ZB  (OFF_WP + (unsigned long long)2*G4H*K_*2)       // 16 KiB zeros (h_{-1})
#define OFF_FLG (OFF_ZB + 16384ull)                             // flags 16 KiB: int flags[8][64]
#define OUT_HN  33554432ull                                     // B*T*H

// ---------------- prep: transpose+cast x, pack+cast weights, zero flags ----
__global__ void prep_kernel(const float* __restrict__ x, const float* __restrict__ Wx,
                            const float* __restrict__ Wh, unsigned char* __restrict__ ws)
{
    unsigned tid = blockIdx.x * 256u + threadIdx.x;   // grid = 16384*256 = 4,194,304
    __hip_bfloat16* xT = (__hip_bfloat16*)(ws + OFF_XT);
    __hip_bfloat16* Wp = (__hip_bfloat16*)(ws + OFF_WP);

    {   // x (B,T,D) fp32 -> xT (T,B,D) bf16, 8 elems/thread (exactly covers 33,554,432)
        unsigned base = tid * 8u;
        unsigned d  = base & (D_ - 1);
        unsigned bt = base >> 9;            // b*T + t
        unsigned t  = bt & (T_ - 1);
        unsigned b  = bt >> 10;
        const float* src = x + base;
        __hip_bfloat16* dst = xT + ((unsigned long long)t * B_ + b) * D_ + d;
        float4 f0 = *(const float4*)(src);
        float4 f1 = *(const float4*)(src + 4);
        dst[0] = __float2bfloat16(f0.x); dst[1] = __float2bfloat16(f0.y);
        dst[2] = __float2bfloat16(f0.z); dst[3] = __float2bfloat16(f0.w);
        dst[4] = __float2bfloat16(f1.x); dst[5] = __float2bfloat16(f1.y);
        dst[6] = __float2bfloat16(f1.z); dst[7] = __float2bfloat16(f1.w);
    }
    {   // W'[l][r][k] = k<512 ? Wx[l][r][k] : Wh[l][r][k-512]  (one elem/thread, exact cover)
        unsigned i = tid;
        unsigned k = i & (K_ - 1);
        unsigned r = (i >> 10) & (G4H - 1);
        unsigned l = i >> 21;
        float v = (k < D_) ? Wx[((unsigned long long)l * G4H + r) * D_ + k]
                           : Wh[((unsigned long long)l * G4H + r) * H_ + (k - D_)];
        Wp[i] = __float2bfloat16(v);
    }
    if (tid < 8192u) ((__hip_bfloat16*)(ws + OFF_ZB))[tid] = __float2bfloat16(0.f);
    if (tid < 4096u) ((int*)(ws + OFF_FLG))[tid] = 0;
}

__device__ __forceinline__ unsigned bf16_bits(float f)
{
    union { __hip_bfloat16 h; unsigned short u; } c;
    c.h = __float2bfloat16(f);
    return (unsigned)c.u;
}

// ---------------- persistent pipelined sLSTM --------------------------------
// grid = 512 blocks x 64 threads. chain = blk&7 (XCD swizzle): chains 0-3 = layer0
// batch-groups, 4-7 = layer1. w = blk>>3 owns hidden units [w*8, w*8+8).
// Sync: per-WG flag array (one int per WG per chain). Arrive = write-through (sc1)
// h stores + s_waitcnt vmcnt(0) + relaxed agent flag store (NO release RMW -> no
// per-step buffer_wbl2 L2 writeback). Depart = per-lane vector atomic load of all
// 64 flags + __all ballot (single hop, no atomic contention).
__launch_bounds__(64, 1)
__global__ void slstm_persist(const float* __restrict__ bx, const float* __restrict__ bh,
                              const float* __restrict__ bext, unsigned char* ws,
                              float* __restrict__ out)
{
    const int lane = threadIdx.x;
    const int n    = lane & 15;
    const int quad = lane >> 4;
    const int blk  = blockIdx.x;
    const int chain = blk & 7;
    const int w     = blk >> 3;          // 0..63
    const int layer = chain >> 2;
    const int g     = chain & 3;
    const int hid_base   = w * 8;
    const int batch_base = g * 16;

    const __hip_bfloat16* xT = (const __hip_bfloat16*)(ws + OFF_XT);
    __hip_bfloat16* h1buf = (__hip_bfloat16*)(ws + OFF_H1);
    __hip_bfloat16* h2buf = (__hip_bfloat16*)(ws + OFF_H2);
    const __hip_bfloat16* Wp = (const __hip_bfloat16*)(ws + OFF_WP);
    const __hip_bfloat16* zb = (const __hip_bfloat16*)(ws + OFF_ZB);
    int* flags = (int*)(ws + OFF_FLG);
    int* myf = flags + chain * 64;       // this chain's 64 per-WG flags
    int* prf = flags + g * 64;           // layer-0 chain of same batch group

    // gate-row mapping: tile0 = [i(hid 0..7) | o(hid 0..7)], tile1 = [f | u]
    const int r0 = (n < 8) ? (hid_base + n) : (2*H_ + hid_base + n - 8);
    const int r1 = (n < 8) ? (H_ + hid_base + n) : (3*H_ + hid_base + n - 8);
    const float bias0 = bx[layer*G4H + r0] + bh[layer*G4H + r0] + bext[layer*G4H + r0];
    const float bias1 = bx[layer*G4H + r1] + bh[layer*G4H + r1] + bext[layer*G4H + r1];

    // preload weights into regs: 64 fragments = 256 regs/lane
    const __hip_bfloat16* Wl = Wp + (unsigned long long)layer * G4H * K_;
    bf16x8 B0[32], B1[32];
#pragma unroll
    for (int kt = 0; kt < 32; ++kt) {
        B0[kt] = *(const bf16x8*)(Wl + (unsigned long long)r0 * K_ + kt*32 + quad*8);
        B1[kt] = *(const bf16x8*)(Wl + (unsigned long long)r1 * K_ + kt*32 + quad*8);
    }

    const __hip_bfloat16* xin  = (layer == 0) ? xT : h1buf;   // K 0..511 source
    __hip_bfloat16*       hout = (layer == 0) ? h1buf : h2buf; // own h history (K 512..1023 src)

    float cst[4] = {0.f,0.f,0.f,0.f}, nst[4] = {0.f,0.f,0.f,0.f};

#pragma unroll 1
    for (int t = 0; t < T_; ++t) {
        bf16x8 a[32];
        const __hip_bfloat16* Ax = xin + ((unsigned long long)t * B_ + batch_base + n) * D_ + quad*8;

        if (layer == 0) {
            // x is static: issue Ax loads BEFORE the spin so their latency hides
#pragma unroll
            for (int kt = 0; kt < 16; ++kt) a[kt] = *(const bf16x8*)(Ax + kt*32);
            asm volatile("" ::: "memory");   // pin the prefetch above the spin
            if (t > 0) {
                for (;;) {
                    int v = __hip_atomic_load(myf + lane, __ATOMIC_RELAXED, __HIP_MEMORY_SCOPE_AGENT);
                    if (__all(v >= t)) break;
                }
            }
        } else {
            // combined poll: own chain h2[t-1] AND producer h1[t]; the two sc1
            // loads are independent so their latencies overlap per iteration
            for (;;) {
                int v1 = __hip_atomic_load(myf + lane, __ATOMIC_RELAXED, __HIP_MEMORY_SCOPE_AGENT);
                int v2 = __hip_atomic_load(prf + lane, __ATOMIC_RELAXED, __HIP_MEMORY_SCOPE_AGENT);
                if (__all((v1 >= t) & (v2 >= t + 1))) break;
            }
        }
        asm volatile("" ::: "memory");   // no data-load hoisting above the spins

        if (layer == 1) {
#pragma unroll
            for (int kt = 0; kt < 16; ++kt) a[kt] = *(const bf16x8*)(Ax + kt*32);
        }
        const __hip_bfloat16* Ah = (t == 0)
            ? (zb + n * H_ + quad*8)
            : (hout + ((unsigned long long)(t-1) * B_ + batch_base + n) * H_ + quad*8);
#pragma unroll
        for (int kt = 0; kt < 16; ++kt) a[16+kt] = *(const bf16x8*)(Ah + kt*32);

        f32x4 acc0 = {0.f,0.f,0.f,0.f}, acc1 = {0.f,0.f,0.f,0.f};
#pragma unroll
        for (int kt = 0; kt < 32; ++kt) {
            acc0 = __builtin_amdgcn_mfma_f32_16x16x32_bf16(a[kt], B0[kt], acc0, 0, 0, 0);
            acc1 = __builtin_amdgcn_mfma_f32_16x16x32_bf16(a[kt], B1[kt], acc1, 0, 0, 0);
        }

        float hv[4];
#pragma unroll
        for (int r = 0; r < 4; ++r) {
            float v0 = acc0[r] + bias0;          // i | o pre-activation
            float v1 = acc1[r] + bias1;          // f | u pre-activation
            float act0 = 1.f / (1.f + __expf(-v0));        // sigmoid (i and o)
            float pre  = (n < 8) ? -v1 : -2.f*v1;
            float s    = 1.f / (1.f + __expf(pre));
            float act1 = (n < 8) ? s : (2.f*s - 1.f);      // f: sigmoid, u: tanh=2σ(2x)-1
            float o_ = __shfl_xor(act0, 8);      // lanes n<8 receive sigmoid(o)
            float u_ = __shfl_xor(act1, 8);      // lanes n<8 receive tanh(u)
            float ci = act1 * cst[r] + act0 * u_;              // f*c + i*u
            float ni = fminf(fmaxf(act1 * nst[r] + act0, 1e-6f), 1e6f);
            cst[r] = ci; nst[r] = ni;
            float ratio = ci / ni;               // |ratio| <= 1 by induction
            float e2 = __expf(-2.f * ratio);
            float th = (1.f - e2) / (1.f + e2);  // tanh(ratio)
            hv[r] = o_ * th;
        }

        // h history store: pack bf16 pairs (hid n, n+1) into u32 and store
        // write-through (sc1, agent scope) so it is L3-visible on vmcnt ack —
        // no L2 writeback needed anywhere.
#pragma unroll
        for (int r = 0; r < 4; ++r) {
            unsigned mybits = bf16_bits(hv[r]);
            unsigned other  = (unsigned)__shfl_xor((int)mybits, 1);
            if ((n & 1) == 0 && n < 8) {
                const int b = batch_base + quad*4 + r;
                unsigned pack = (mybits & 0xffffu) | (other << 16);
                unsigned* p = (unsigned*)(hout + ((unsigned long long)t * B_ + b) * H_ + hid_base + n);
                __hip_atomic_store(p, pack, __ATOMIC_RELAXED, __HIP_MEMORY_SCOPE_AGENT);
            }
        }

        if (n < 8) {
            const int hid = hid_base + n;
            if (layer == 1) {
#pragma unroll
                for (int r = 0; r < 4; ++r) {
                    const int b = batch_base + quad*4 + r;
                    out[((unsigned long long)b * T_ + t) * H_ + hid] = hv[r];  // plain (kernel-end flush)
                }
            }
            if (t == T_ - 1) {
#pragma unroll
                for (int r = 0; r < 4; ++r) {
                    const int b = batch_base + quad*4 + r;
                    unsigned long long so = OUT_HN + (unsigned long long)layer*32768ull
                                          + (unsigned long long)b*H_ + hid;
                    out[so]            = hv[r];   // hN
                    out[so +  65536ull] = cst[r]; // cN
                    out[so + 131072ull] = nst[r]; // nN
                }
            }
        }

        // arrive: wait for the sc1 h-stores to reach the coherence point, then
        // publish this WG's progress with a relaxed agent store (sc1). No RMW,
        // no buffer_wbl2.
        asm volatile("s_waitcnt vmcnt(0)" ::: "memory");
        if (lane == 0)
            __hip_atomic_store(myf + w, t + 1, __ATOMIC_RELAXED, __HIP_MEMORY_SCOPE_AGENT);
    }
}

extern "C" void kernel_launch(void* const* d_in, const int* in_sizes, int n_in,
                              void* d_out, int out_size, void* d_ws, size_t ws_size,
                              hipStream_t stream)
{
    const float* x    = (const float*)d_in[0];
    const float* Wx   = (const float*)d_in[1];
    const float* bx   = (const float*)d_in[2];
    const float* Wh   = (const float*)d_in[3];
    const float* bh   = (const float*)d_in[4];
    const float* bext = (const float*)d_in[5];
    float* out = (float*)d_out;
    unsigned char* ws = (unsigned char*)d_ws;
    // needs ~200 MiB of workspace (xT 64M + h1 64M + h2 64M + W' 8M + misc)

    prep_kernel<<<16384, 256, 0, stream>>>(x, Wx, Wh, ws);
    slstm_persist<<<512, 64, 0, stream>>>(bx, bh, bext, ws, out);
}